// Round 7
// baseline (26.121 us; speedup 1.0000x reference)
//
#include <hip/hip_runtime.h>

#define BB   256
#define NN   128
#define AA   15
#define HH   32
#define MIDD 256

typedef _Float16 h2_t __attribute__((ext_vector_type(2)));

struct MsgS {                       // messenger-block shared state
    _Float16 vh[NN][HH];            // 8 KB  f16 v
    float    p[NN][HH];             // 16 KB swizzled p
    float    part[4][8][16][8];     // 16 KB stage-1 partials
    float    msg[NN];
};
struct CriS {                       // critic-block shared state (4 batch elems)
    float obs4[4][NN];              // 2 KB
    float cpart[4][4][MIDD];        // 16 KB  [k-slice][batch][out]
    float h4[2][4][MIDD];           // 8 KB   activations
};

// aux_s layout: [0:128) mw1 | [128:224) aw1(rows0-2) | [224:256) ab1
//               [256:288) aw2 | [288:320) mw2 | [320:352) mb1 | [352] mb2 | [353] ab2
__global__ __launch_bounds__(512, 4) void gacq_v7(
    const float* __restrict__ obs,
    const float* __restrict__ mw1, const float* __restrict__ mb1,
    const float* __restrict__ mw2, const float* __restrict__ mb2,
    const float* __restrict__ aw1, const float* __restrict__ ab1,
    const float* __restrict__ aw2, const float* __restrict__ ab2,
    const float* __restrict__ cw1, const float* __restrict__ cb1,
    const float* __restrict__ cw2, const float* __restrict__ cb2,
    const float* __restrict__ cw3, const float* __restrict__ cb3,
    const float* __restrict__ cw4, const float* __restrict__ cb4,
    float* __restrict__ out)
{
    __shared__ __align__(16) float aux_s[356];
    __shared__ __align__(16) float obs_s[NN];
    __shared__ __align__(16) union { MsgS m; CriS c; } u_s;

    const int blk = blockIdx.x;
    const int t   = threadIdx.x;

    if (blk < BB) {
        // ===================== messenger + actor (one b per block) =====================
        const int b = blk;

        if (t < 354) {
            float v;
            if      (t < 128) v = mw1[t];
            else if (t < 224) v = aw1[t - 128];
            else if (t < 256) v = ab1[t - 224];
            else if (t < 288) v = aw2[t - 256];
            else if (t < 320) v = mw2[t - 288];
            else if (t < 352) v = mb1[t - 320];
            else if (t == 352) v = mb2[0];
            else               v = ab2[0];
            aux_s[t] = v;
        }
        if (t < NN) obs_s[t] = obs[b * NN + t];
        __syncthreads();

        // v[j][k] as f16 pairs
        for (int e = t; e < NN * HH / 2; e += 512) {
            const int   j  = e >> 4, kp = e & 15;
            const int   k0 = kp * 2;
            const float cj = (float)j * (1.0f / (float)NN);
            const float v0 = obs_s[j] * aux_s[64 + k0]     + cj * aux_s[96 + k0]     + aux_s[320 + k0];
            const float v1 = obs_s[j] * aux_s[64 + k0 + 1] + cj * aux_s[96 + k0 + 1] + aux_s[320 + k0 + 1];
            h2_t p; p[0] = (_Float16)v0; p[1] = (_Float16)v1;
            *(h2_t*)&u_s.m.vh[j][k0] = p;
        }

        const int kg = t & 7;           // k = kg*4 + kk
        const int rg = (t >> 3) & 15;   // rows rg*8 + rr
        const int jg = t >> 7;          // j in [jg*32, jg*32+32)

        h2_t u2[8][2], w2h[2];
        {
            w2h[0][0] = (_Float16)aux_s[288 + kg * 4 + 0];
            w2h[0][1] = (_Float16)aux_s[288 + kg * 4 + 1];
            w2h[1][0] = (_Float16)aux_s[288 + kg * 4 + 2];
            w2h[1][1] = (_Float16)aux_s[288 + kg * 4 + 3];
        }
#pragma unroll
        for (int rr = 0; rr < 8; ++rr) {
            const int   row = rg * 8 + rr;
            const float ob  = obs_s[row];
            const float cr  = (float)row * (1.0f / (float)NN);
#pragma unroll
            for (int kp = 0; kp < 2; ++kp) {
                const int k0 = kg * 4 + kp * 2;
                u2[rr][kp][0] = (_Float16)(ob * aux_s[k0]     + cr * aux_s[32 + k0]);
                u2[rr][kp][1] = (_Float16)(ob * aux_s[k0 + 1] + cr * aux_s[32 + k0 + 1]);
            }
        }
        __syncthreads();   // v ready

        // ---- stage 1: 8 rows x 4 k x 32 j via packed-f16 + fdot2(f32 acc) ----
        float acc[8];
#pragma unroll
        for (int rr = 0; rr < 8; ++rr) acc[rr] = 0.f;
        const int j0 = jg * 32;
        {
            const h2_t   zero  = (h2_t)((_Float16)0);
            const uint2* vbase = (const uint2*)&u_s.m.vh[0][kg * 4];   // row stride 8 uint2
            uint2 vc = vbase[j0 * 8];
#pragma unroll 4
            for (int jj = 0; jj < 32; ++jj) {
                const int   nj = j0 + ((jj + 1) & 31);
                const uint2 vn = vbase[nj * 8];
                const h2_t  va = __builtin_bit_cast(h2_t, vc.x);
                const h2_t  vb = __builtin_bit_cast(h2_t, vc.y);
#pragma unroll
                for (int rr = 0; rr < 8; ++rr) {
                    h2_t s0 = u2[rr][0] + va;
                    h2_t s1 = u2[rr][1] + vb;
                    s0 = __builtin_elementwise_max(s0, zero);
                    s1 = __builtin_elementwise_max(s1, zero);
                    acc[rr] = __builtin_amdgcn_fdot2(s0, w2h[0], acc[rr], false);
                    acc[rr] = __builtin_amdgcn_fdot2(s1, w2h[1], acc[rr], false);
                }
                vc = vn;
            }
        }
        *(float4*)&u_s.m.part[jg][kg][rg][0] = make_float4(acc[0], acc[1], acc[2], acc[3]);
        *(float4*)&u_s.m.part[jg][kg][rg][4] = make_float4(acc[4], acc[5], acc[6], acc[7]);
        __syncthreads();

        if (t < NN) {
            float m = (float)NN * aux_s[352];
#pragma unroll
            for (int g = 0; g < 4; ++g)
#pragma unroll
                for (int q = 0; q < 8; ++q)
                    m += u_s.m.part[g][q][t >> 3][t & 7];
            u_s.m.msg[t] = m;
        }
        __syncthreads();

        // ---- stage p: p[row][k] chunk-XOR-swizzled ----
#pragma unroll
        for (int it = 0; it < 2; ++it) {
            const int   row = t & 127;
            const int   c   = (t >> 7) + it * 4;
            const float mi  = u_s.m.msg[row];
            const float cr  = (float)row * (1.0f / (float)NN);
            const int   k0  = c * 4;
            float4 p;
            p.x = mi * aux_s[128 + k0 + 0] + cr * aux_s[160 + k0 + 0] + aux_s[224 + k0 + 0];
            p.y = mi * aux_s[128 + k0 + 1] + cr * aux_s[160 + k0 + 1] + aux_s[224 + k0 + 1];
            p.z = mi * aux_s[128 + k0 + 2] + cr * aux_s[160 + k0 + 2] + aux_s[224 + k0 + 2];
            p.w = mi * aux_s[128 + k0 + 3] + cr * aux_s[160 + k0 + 3] + aux_s[224 + k0 + 3];
            *(float4*)&u_s.m.p[row][(c ^ (row & 7)) * 4] = p;
        }
        __syncthreads();

        // ---- stage 2: a = t>>5 (16 groups, a=15 dummy), sub = t&31, rows sub+32m ----
        {
            const int   a   = t >> 5;
            const int   sub = t & 31;
            const float fa  = (float)a;
            float qa[HH];
#pragma unroll
            for (int k = 0; k < HH; ++k) qa[k] = fa * aux_s[192 + k];
            float s0 = 0.f, s1 = 0.f, s2 = 0.f, s3 = 0.f;
#pragma unroll
            for (int m = 0; m < 4; ++m) {
                const int row = sub + 32 * m;
                const int sw  = row & 7;
#pragma unroll
                for (int c = 0; c < 8; ++c) {
                    const float4 p4 = *(const float4*)&u_s.m.p[row][(c ^ sw) * 4];
                    const float4 w4 = *(const float4*)&aux_s[256 + c * 4];
                    const int    k0 = c * 4;
                    s0 += fmaxf(p4.x + qa[k0 + 0], 0.f) * w4.x;
                    s1 += fmaxf(p4.y + qa[k0 + 1], 0.f) * w4.y;
                    s2 += fmaxf(p4.z + qa[k0 + 2], 0.f) * w4.z;
                    s3 += fmaxf(p4.w + qa[k0 + 3], 0.f) * w4.w;
                }
            }
            float s = (s0 + s1) + (s2 + s3);
#pragma unroll
            for (int off = 1; off < 32; off <<= 1) s += __shfl_xor(s, off);
            if (sub == 0 && a < AA)
                out[b * AA + a] = s + (float)NN * aux_s[353];
        }
    } else {
        // ===================== critic: 4 batch elems per block =====================
        const int b0 = (blk - BB) * 4;

        for (int e = t; e < 4 * NN; e += 512)
            u_s.c.obs4[e >> 7][e & 127] = obs[(b0 + (e >> 7)) * NN + (e & 127)];
        __syncthreads();

        const int q  = t & 63;          // output quad: units 4q..4q+3
        const int pp = (t >> 6) & 1;    // batch pair
        const int s  = t >> 7;          // k-slice 0..3
        const int ba = pp * 2, bb2 = pp * 2 + 1;

        {   // layer 1: K=128, slice of 32
            float4 A0 = make_float4(0.f, 0.f, 0.f, 0.f);
            float4 A1 = make_float4(0.f, 0.f, 0.f, 0.f);
            const int k0 = s * 32;
#pragma unroll 8
            for (int k = k0; k < k0 + 32; ++k) {
                const float4 w  = *(const float4*)&cw1[k * MIDD + q * 4];
                const float  h0 = u_s.c.obs4[ba][k];
                const float  h1 = u_s.c.obs4[bb2][k];
                A0.x += h0 * w.x; A0.y += h0 * w.y; A0.z += h0 * w.z; A0.w += h0 * w.w;
                A1.x += h1 * w.x; A1.y += h1 * w.y; A1.z += h1 * w.z; A1.w += h1 * w.w;
            }
            *(float4*)&u_s.c.cpart[s][ba][q * 4]  = A0;
            *(float4*)&u_s.c.cpart[s][bb2][q * 4] = A1;
        }
        __syncthreads();
        for (int e = t; e < 4 * MIDD; e += 512) {
            const int bb = e >> 8, o = e & 255;
            float sum = cb1[o];
#pragma unroll
            for (int ss = 0; ss < 4; ++ss) sum += u_s.c.cpart[ss][bb][o];
            u_s.c.h4[0][bb][o] = fmaxf(sum, 0.f);
        }
        __syncthreads();

        {   // layer 2: K=256, slice of 64
            float4 A0 = make_float4(0.f, 0.f, 0.f, 0.f);
            float4 A1 = make_float4(0.f, 0.f, 0.f, 0.f);
            const int k0 = s * 64;
#pragma unroll 8
            for (int k = k0; k < k0 + 64; ++k) {
                const float4 w  = *(const float4*)&cw2[k * MIDD + q * 4];
                const float  h0 = u_s.c.h4[0][ba][k];
                const float  h1 = u_s.c.h4[0][bb2][k];
                A0.x += h0 * w.x; A0.y += h0 * w.y; A0.z += h0 * w.z; A0.w += h0 * w.w;
                A1.x += h1 * w.x; A1.y += h1 * w.y; A1.z += h1 * w.z; A1.w += h1 * w.w;
            }
            *(float4*)&u_s.c.cpart[s][ba][q * 4]  = A0;
            *(float4*)&u_s.c.cpart[s][bb2][q * 4] = A1;
        }
        __syncthreads();
        for (int e = t; e < 4 * MIDD; e += 512) {
            const int bb = e >> 8, o = e & 255;
            float sum = cb2[o];
#pragma unroll
            for (int ss = 0; ss < 4; ++ss) sum += u_s.c.cpart[ss][bb][o];
            u_s.c.h4[1][bb][o] = fmaxf(sum, 0.f);
        }
        __syncthreads();

        {   // layer 3: K=256, slice of 64
            float4 A0 = make_float4(0.f, 0.f, 0.f, 0.f);
            float4 A1 = make_float4(0.f, 0.f, 0.f, 0.f);
            const int k0 = s * 64;
#pragma unroll 8
            for (int k = k0; k < k0 + 64; ++k) {
                const float4 w  = *(const float4*)&cw3[k * MIDD + q * 4];
                const float  h0 = u_s.c.h4[1][ba][k];
                const float  h1 = u_s.c.h4[1][bb2][k];
                A0.x += h0 * w.x; A0.y += h0 * w.y; A0.z += h0 * w.z; A0.w += h0 * w.w;
                A1.x += h1 * w.x; A1.y += h1 * w.y; A1.z += h1 * w.z; A1.w += h1 * w.w;
            }
            *(float4*)&u_s.c.cpart[s][ba][q * 4]  = A0;
            *(float4*)&u_s.c.cpart[s][bb2][q * 4] = A1;
        }
        __syncthreads();
        // layer-3 finish + head product into h4[0]
        for (int e = t; e < 4 * MIDD; e += 512) {
            const int bb = e >> 8, o = e & 255;
            float sum = cb3[o];
#pragma unroll
            for (int ss = 0; ss < 4; ++ss) sum += u_s.c.cpart[ss][bb][o];
            u_s.c.h4[0][bb][o] = fmaxf(sum, 0.f) * cw4[o];
        }
        __syncthreads();
        // per-batch 256-value reduce: wave w (0..3) handles batch w
        {
            const int wv   = t >> 6;
            const int lane = t & 63;
            if (wv < 4) {
                float sum = u_s.c.h4[0][wv][lane]       + u_s.c.h4[0][wv][lane + 64]
                          + u_s.c.h4[0][wv][lane + 128] + u_s.c.h4[0][wv][lane + 192];
#pragma unroll
                for (int off = 32; off > 0; off >>= 1) sum += __shfl_xor(sum, off);
                if (lane == 0) out[BB * AA + b0 + wv] = sum + cb4[0];
            }
        }
    }
}

extern "C" void kernel_launch(void* const* d_in, const int* in_sizes, int n_in,
                              void* d_out, int out_size, void* d_ws, size_t ws_size,
                              hipStream_t stream) {
    const float* obs = (const float*)d_in[0];
    const float* mw1 = (const float*)d_in[1];
    const float* mb1 = (const float*)d_in[2];
    const float* mw2 = (const float*)d_in[3];
    const float* mb2 = (const float*)d_in[4];
    const float* aw1 = (const float*)d_in[5];
    const float* ab1 = (const float*)d_in[6];
    const float* aw2 = (const float*)d_in[7];
    const float* ab2 = (const float*)d_in[8];
    const float* cw1 = (const float*)d_in[9];
    const float* cb1 = (const float*)d_in[10];
    const float* cw2 = (const float*)d_in[11];
    const float* cb2 = (const float*)d_in[12];
    const float* cw3 = (const float*)d_in[13];
    const float* cb3 = (const float*)d_in[14];
    const float* cw4 = (const float*)d_in[15];
    const float* cb4 = (const float*)d_in[16];
    float* out = (float*)d_out;

    gacq_v7<<<dim3(BB + BB / 4), dim3(512), 0, stream>>>(
        obs, mw1, mb1, mw2, mb2, aw1, ab1, aw2, ab2,
        cw1, cb1, cw2, cb2, cw3, cb3, cw4, cb4, out);
}

// Round 8
// 18.832 us; speedup vs baseline: 1.3870x; 1.3870x over previous
//
#include <hip/hip_runtime.h>

#define BB   256
#define NN   128
#define AA   15
#define HH   32
#define MIDD 256

typedef _Float16 h2_t __attribute__((ext_vector_type(2)));

// spin barrier among a subset of waves (only that subset touches ctr)
__device__ __forceinline__ void spin_bar(int* ctr, int target) {
    __threadfence_block();
    if ((threadIdx.x & 63) == 0) atomicAdd(ctr, 1);
    while (__hip_atomic_load(ctr, __ATOMIC_ACQUIRE, __HIP_MEMORY_SCOPE_WORKGROUP) < target)
        __builtin_amdgcn_s_sleep(1);
    __threadfence_block();
}

// aux_s layout: [0:128) mw1 | [128:224) aw1(rows0-2) | [224:256) ab1
//               [256:288) aw2 | [288:320) mw2 | [320:352) mb1 | [352] mb2 | [353] ab2
__global__ __launch_bounds__(1024, 4) void gacq_v8(
    const float* __restrict__ obs,
    const float* __restrict__ mw1, const float* __restrict__ mb1,
    const float* __restrict__ mw2, const float* __restrict__ mb2,
    const float* __restrict__ aw1, const float* __restrict__ ab1,
    const float* __restrict__ aw2, const float* __restrict__ ab2,
    const float* __restrict__ cw1, const float* __restrict__ cb1,
    const float* __restrict__ cw2, const float* __restrict__ cb2,
    const float* __restrict__ cw3, const float* __restrict__ cb3,
    const float* __restrict__ cw4, const float* __restrict__ cb4,
    float* __restrict__ out)
{
    __shared__ __align__(16) float    aux_s[356];
    __shared__ __align__(16) float    obs_s[NN];
    __shared__ __align__(16) _Float16 vh_s[NN][HH];          // 8 KB  f16 v
    __shared__ __align__(16) float4   p4_s[8][NN];           // 8 KB (chunk-major p)
    __shared__ __align__(16) float    part_s[4][8][16][8];   // 16 KB stage-1 partials
    __shared__ __align__(16) float    msg_s[NN];
    __shared__ __align__(16) float    cpart_s[8][MIDD];      // 8 KB critic partials
    __shared__ __align__(16) float    h_s[2][MIDD];          // 2 KB
    __shared__ float red_s[4];
    __shared__ int   mbar, cbar;

    const int b = blockIdx.x;
    const int t = threadIdx.x;

    if (t == 0) { mbar = 0; cbar = 0; }
    if (t < 354) {                                // msg half stages small weights
        float v;
        if      (t < 128) v = mw1[t];
        else if (t < 224) v = aw1[t - 128];
        else if (t < 256) v = ab1[t - 224];
        else if (t < 288) v = aw2[t - 256];
        else if (t < 320) v = mw2[t - 288];
        else if (t < 352) v = mb1[t - 320];
        else if (t == 352) v = mb2[0];
        else               v = ab2[0];
        aux_s[t] = v;
    }
    if (t >= 512 && t < 512 + NN) obs_s[t - 512] = obs[b * NN + (t - 512)];
    __syncthreads();   // the ONLY full-block barrier

    if (t < 512) {
        // ============== messenger + actor: waves 0-7 ==============
        // v[j][k] as f16 pairs
        for (int e = t; e < NN * HH / 2; e += 512) {
            const int   j  = e >> 4, kp = e & 15;
            const int   k0 = kp * 2;
            const float cj = (float)j * (1.0f / (float)NN);
            const float v0 = obs_s[j] * aux_s[64 + k0]     + cj * aux_s[96 + k0]     + aux_s[320 + k0];
            const float v1 = obs_s[j] * aux_s[64 + k0 + 1] + cj * aux_s[96 + k0 + 1] + aux_s[320 + k0 + 1];
            h2_t p; p[0] = (_Float16)v0; p[1] = (_Float16)v1;
            *(h2_t*)&vh_s[j][k0] = p;
        }

        const int kg = t & 7;           // k = kg*4 + kk
        const int rg = (t >> 3) & 15;   // rows rg*8 + rr
        const int jg = t >> 7;          // j in [jg*32, jg*32+32)

        h2_t u2[8][2], w2h[2];
        w2h[0][0] = (_Float16)aux_s[288 + kg * 4 + 0];
        w2h[0][1] = (_Float16)aux_s[288 + kg * 4 + 1];
        w2h[1][0] = (_Float16)aux_s[288 + kg * 4 + 2];
        w2h[1][1] = (_Float16)aux_s[288 + kg * 4 + 3];
#pragma unroll
        for (int rr = 0; rr < 8; ++rr) {
            const int   row = rg * 8 + rr;
            const float ob  = obs_s[row];
            const float cr  = (float)row * (1.0f / (float)NN);
#pragma unroll
            for (int kp = 0; kp < 2; ++kp) {
                const int k0 = kg * 4 + kp * 2;
                u2[rr][kp][0] = (_Float16)(ob * aux_s[k0]     + cr * aux_s[32 + k0]);
                u2[rr][kp][1] = (_Float16)(ob * aux_s[k0 + 1] + cr * aux_s[32 + k0 + 1]);
            }
        }
        spin_bar(&mbar, 8);   // v ready

        // ---- stage 1: 8 rows x 4 k x 32 j via packed-f16 + fdot2(f32 acc) ----
        float acc[8];
#pragma unroll
        for (int rr = 0; rr < 8; ++rr) acc[rr] = 0.f;
        const int j0 = jg * 32;
        {
            const h2_t   zero  = (h2_t)((_Float16)0);
            const uint2* vbase = (const uint2*)&vh_s[0][kg * 4];   // row stride 8 uint2
            uint2 vc = vbase[j0 * 8];
#pragma unroll 4
            for (int jj = 0; jj < 32; ++jj) {
                const int   nj = j0 + ((jj + 1) & 31);
                const uint2 vn = vbase[nj * 8];
                const h2_t  va = __builtin_bit_cast(h2_t, vc.x);
                const h2_t  vb = __builtin_bit_cast(h2_t, vc.y);
#pragma unroll
                for (int rr = 0; rr < 8; ++rr) {
                    h2_t s0 = u2[rr][0] + va;
                    h2_t s1 = u2[rr][1] + vb;
                    s0 = __builtin_elementwise_max(s0, zero);
                    s1 = __builtin_elementwise_max(s1, zero);
                    acc[rr] = __builtin_amdgcn_fdot2(s0, w2h[0], acc[rr], false);
                    acc[rr] = __builtin_amdgcn_fdot2(s1, w2h[1], acc[rr], false);
                }
                vc = vn;
            }
        }
        *(float4*)&part_s[jg][kg][rg][0] = make_float4(acc[0], acc[1], acc[2], acc[3]);
        *(float4*)&part_s[jg][kg][rg][4] = make_float4(acc[4], acc[5], acc[6], acc[7]);
        spin_bar(&mbar, 16);

        if (t < NN) {
            float m = (float)NN * aux_s[352];
#pragma unroll
            for (int g = 0; g < 4; ++g)
#pragma unroll
                for (int q = 0; q < 8; ++q)
                    m += part_s[g][q][t >> 3][t & 7];
            msg_s[t] = m;
        }
        spin_bar(&mbar, 24);

        // ---- stage p: chunk-major p4[c][row] (conflict-free) ----
#pragma unroll
        for (int it = 0; it < 2; ++it) {
            const int   row = t & 127;
            const int   c   = (t >> 7) + it * 4;
            const float mi  = msg_s[row];
            const float cr  = (float)row * (1.0f / (float)NN);
            const int   k0  = c * 4;
            float4 p;
            p.x = mi * aux_s[128 + k0 + 0] + cr * aux_s[160 + k0 + 0] + aux_s[224 + k0 + 0];
            p.y = mi * aux_s[128 + k0 + 1] + cr * aux_s[160 + k0 + 1] + aux_s[224 + k0 + 1];
            p.z = mi * aux_s[128 + k0 + 2] + cr * aux_s[160 + k0 + 2] + aux_s[224 + k0 + 2];
            p.w = mi * aux_s[128 + k0 + 3] + cr * aux_s[160 + k0 + 3] + aux_s[224 + k0 + 3];
            p4_s[c][row] = p;
        }
        spin_bar(&mbar, 32);

        // ---- stage 2: a = t>>5 (16 groups, a=15 dummy), sub = t&31, rows sub+32m ----
        {
            const int   a   = t >> 5;
            const int   sub = t & 31;
            const float fa  = (float)a;
            float qa[HH];
#pragma unroll
            for (int k = 0; k < HH; ++k) qa[k] = fa * aux_s[192 + k];
            float s0 = 0.f, s1 = 0.f, s2 = 0.f, s3 = 0.f;
#pragma unroll
            for (int m = 0; m < 4; ++m) {
                const int row = sub + 32 * m;
#pragma unroll
                for (int c = 0; c < 8; ++c) {
                    const float4 p4 = p4_s[c][row];
                    const float4 w4 = *(const float4*)&aux_s[256 + c * 4];
                    const int    k0 = c * 4;
                    s0 += fmaxf(p4.x + qa[k0 + 0], 0.f) * w4.x;
                    s1 += fmaxf(p4.y + qa[k0 + 1], 0.f) * w4.y;
                    s2 += fmaxf(p4.z + qa[k0 + 2], 0.f) * w4.z;
                    s3 += fmaxf(p4.w + qa[k0 + 3], 0.f) * w4.w;
                }
            }
            float s = (s0 + s1) + (s2 + s3);
#pragma unroll
            for (int off = 1; off < 32; off <<= 1) s += __shfl_xor(s, off);
            if (sub == 0 && a < AA)
                out[b * AA + a] = s + (float)NN * aux_s[353];
        }
    } else {
        // ============== critic: waves 8-15, same batch element ==============
        const int tt = t - 512;
        const int q  = tt & 63;     // output quad: units 4q..4q+3
        const int s  = tt >> 6;     // k-slice 0..7

        {   // layer 1: 128 -> 256, k-slice of 16
            float4 acc = make_float4(0.f, 0.f, 0.f, 0.f);
            const int k0 = s * 16;
#pragma unroll 8
            for (int k = k0; k < k0 + 16; ++k) {
                const float4 w = *(const float4*)&cw1[k * MIDD + q * 4];
                const float  h = obs_s[k];
                acc.x += h * w.x; acc.y += h * w.y; acc.z += h * w.z; acc.w += h * w.w;
            }
            *(float4*)&cpart_s[s][q * 4] = acc;
        }
        spin_bar(&cbar, 8);
        if (tt < MIDD) {
            float sum = cb1[tt];
#pragma unroll
            for (int s8 = 0; s8 < 8; ++s8) sum += cpart_s[s8][tt];
            h_s[0][tt] = fmaxf(sum, 0.f);
        }
        spin_bar(&cbar, 16);

        {   // layer 2: 256 -> 256, k-slice of 32
            float4 acc = make_float4(0.f, 0.f, 0.f, 0.f);
            const int k0 = s * 32;
#pragma unroll 8
            for (int k = k0; k < k0 + 32; ++k) {
                const float4 w = *(const float4*)&cw2[k * MIDD + q * 4];
                const float  h = h_s[0][k];
                acc.x += h * w.x; acc.y += h * w.y; acc.z += h * w.z; acc.w += h * w.w;
            }
            *(float4*)&cpart_s[s][q * 4] = acc;
        }
        spin_bar(&cbar, 24);
        if (tt < MIDD) {
            float sum = cb2[tt];
#pragma unroll
            for (int s8 = 0; s8 < 8; ++s8) sum += cpart_s[s8][tt];
            h_s[1][tt] = fmaxf(sum, 0.f);
        }
        spin_bar(&cbar, 32);

        {   // layer 3: 256 -> 256, k-slice of 32
            float4 acc = make_float4(0.f, 0.f, 0.f, 0.f);
            const int k0 = s * 32;
#pragma unroll 8
            for (int k = k0; k < k0 + 32; ++k) {
                const float4 w = *(const float4*)&cw3[k * MIDD + q * 4];
                const float  h = h_s[1][k];
                acc.x += h * w.x; acc.y += h * w.y; acc.z += h * w.z; acc.w += h * w.w;
            }
            *(float4*)&cpart_s[s][q * 4] = acc;
        }
        spin_bar(&cbar, 40);
        if (tt < MIDD) {   // layer-3 finish + head product
            float sum = cb3[tt];
#pragma unroll
            for (int s8 = 0; s8 < 8; ++s8) sum += cpart_s[s8][tt];
            h_s[0][tt] = fmaxf(sum, 0.f) * cw4[tt];
        }
        spin_bar(&cbar, 48);
        if (tt < MIDD) {
            float pv = h_s[0][tt];
#pragma unroll
            for (int off = 32; off > 0; off >>= 1) pv += __shfl_xor(pv, off);
            if ((tt & 63) == 0) red_s[tt >> 6] = pv;
        }
        spin_bar(&cbar, 56);
        if (tt == 0)
            out[BB * AA + b] = red_s[0] + red_s[1] + red_s[2] + red_s[3] + cb4[0];
    }
}

extern "C" void kernel_launch(void* const* d_in, const int* in_sizes, int n_in,
                              void* d_out, int out_size, void* d_ws, size_t ws_size,
                              hipStream_t stream) {
    const float* obs = (const float*)d_in[0];
    const float* mw1 = (const float*)d_in[1];
    const float* mb1 = (const float*)d_in[2];
    const float* mw2 = (const float*)d_in[3];
    const float* mb2 = (const float*)d_in[4];
    const float* aw1 = (const float*)d_in[5];
    const float* ab1 = (const float*)d_in[6];
    const float* aw2 = (const float*)d_in[7];
    const float* ab2 = (const float*)d_in[8];
    const float* cw1 = (const float*)d_in[9];
    const float* cb1 = (const float*)d_in[10];
    const float* cw2 = (const float*)d_in[11];
    const float* cb2 = (const float*)d_in[12];
    const float* cw3 = (const float*)d_in[13];
    const float* cb3 = (const float*)d_in[14];
    const float* cw4 = (const float*)d_in[15];
    const float* cb4 = (const float*)d_in[16];
    float* out = (float*)d_out;

    gacq_v8<<<dim3(BB), dim3(1024), 0, stream>>>(
        obs, mw1, mb1, mw2, mb2, aw1, ab1, aw2, ab2,
        cw1, cb1, cw2, cb2, cw3, cb3, cw4, cb4, out);
}

// Round 9
// 17.162 us; speedup vs baseline: 1.5220x; 1.0973x over previous
//
#include <hip/hip_runtime.h>

#define BB    256
#define NN    128
#define AA    15
#define HH    32
#define MIDD  256
#define NCRIT 16    // critic blocks, 16 batch elems each

typedef _Float16 h2_t  __attribute__((ext_vector_type(2)));
typedef _Float16 f16x8 __attribute__((ext_vector_type(8)));
typedef float    f32x4 __attribute__((ext_vector_type(4)));

struct MsgS {
    _Float16 vh[NN][HH];        // 8 KB  f16 v
    float4   p4[8][NN];         // 8 KB  chunk-major p (conflict-free, v8-verified)
    float    part[4][16][8];    // 2 KB  jg-partials (kg reduced in-register)
    float    msg[NN];
};
struct CriS {
    _Float16 hA[2][16][264];    // 16.9 KB padded activation ping-pong
};

// aux layout: [0:128) mw1 | [128:224) aw1(rows0-2) | [224:256) ab1
//             [256:288) aw2 | [288:320) mw2 | [320:352) mb1 | [352] mb2 | [353] ab2
__global__ __launch_bounds__(512, 4) void gacq_v9(
    const float* __restrict__ obs,
    const float* __restrict__ mw1, const float* __restrict__ mb1,
    const float* __restrict__ mw2, const float* __restrict__ mb2,
    const float* __restrict__ aw1, const float* __restrict__ ab1,
    const float* __restrict__ aw2, const float* __restrict__ ab2,
    const float* __restrict__ cw1, const float* __restrict__ cb1,
    const float* __restrict__ cw2, const float* __restrict__ cb2,
    const float* __restrict__ cw3, const float* __restrict__ cb3,
    const float* __restrict__ cw4, const float* __restrict__ cb4,
    float* __restrict__ out)
{
    __shared__ __align__(16) float aux_s[356];
    __shared__ __align__(16) float obs_s[NN];
    __shared__ __align__(16) union { MsgS m; CriS c; } u_s;

    const int blk  = blockIdx.x;
    const int t    = threadIdx.x;
    const int lane = t & 63;

    if (blk >= NCRIT) {
        // ===================== messenger + actor (one b per block) =====================
        const int b = blk - NCRIT;

        if (t < 354) {
            float v;
            if      (t < 128) v = mw1[t];
            else if (t < 224) v = aw1[t - 128];
            else if (t < 256) v = ab1[t - 224];
            else if (t < 288) v = aw2[t - 256];
            else if (t < 320) v = mw2[t - 288];
            else if (t < 352) v = mb1[t - 320];
            else if (t == 352) v = mb2[0];
            else               v = ab2[0];
            aux_s[t] = v;
        }
        if (t < NN) obs_s[t] = obs[b * NN + t];
        __syncthreads();

        // v[j][k] as f16 pairs
        for (int e = t; e < NN * HH / 2; e += 512) {
            const int   j  = e >> 4, kp = e & 15;
            const int   k0 = kp * 2;
            const float cj = (float)j * (1.0f / (float)NN);
            const float v0 = obs_s[j] * aux_s[64 + k0]     + cj * aux_s[96 + k0]     + aux_s[320 + k0];
            const float v1 = obs_s[j] * aux_s[64 + k0 + 1] + cj * aux_s[96 + k0 + 1] + aux_s[320 + k0 + 1];
            h2_t p; p[0] = (_Float16)v0; p[1] = (_Float16)v1;
            *(h2_t*)&u_s.m.vh[j][k0] = p;
        }

        const int kg = t & 7;           // k = kg*4 + kk  (lane bits 0-2)
        const int rg = (t >> 3) & 15;   // rows rg*8 + rr
        const int jg = t >> 7;          // j in [jg*32, jg*32+32)

        h2_t u2[8][2], w2h[2];
        w2h[0][0] = (_Float16)aux_s[288 + kg * 4 + 0];
        w2h[0][1] = (_Float16)aux_s[288 + kg * 4 + 1];
        w2h[1][0] = (_Float16)aux_s[288 + kg * 4 + 2];
        w2h[1][1] = (_Float16)aux_s[288 + kg * 4 + 3];
#pragma unroll
        for (int rr = 0; rr < 8; ++rr) {
            const int   row = rg * 8 + rr;
            const float ob  = obs_s[row];
            const float cr  = (float)row * (1.0f / (float)NN);
#pragma unroll
            for (int kp = 0; kp < 2; ++kp) {
                const int k0 = kg * 4 + kp * 2;
                u2[rr][kp][0] = (_Float16)(ob * aux_s[k0]     + cr * aux_s[32 + k0]);
                u2[rr][kp][1] = (_Float16)(ob * aux_s[k0 + 1] + cr * aux_s[32 + k0 + 1]);
            }
        }
        __syncthreads();   // v ready

        // ---- stage 1: 8 rows x 4 k x 32 j via packed-f16 + fdot2(f32 acc) ----
        float acc[8];
#pragma unroll
        for (int rr = 0; rr < 8; ++rr) acc[rr] = 0.f;
        const int j0 = jg * 32;
        {
            const h2_t   zero  = (h2_t)((_Float16)0);
            const uint2* vbase = (const uint2*)&u_s.m.vh[0][kg * 4];   // row stride 8 uint2
            uint2 vc = vbase[j0 * 8];
#pragma unroll 4
            for (int jj = 0; jj < 32; ++jj) {
                const int   nj = j0 + ((jj + 1) & 31);
                const uint2 vn = vbase[nj * 8];
                const h2_t  va = __builtin_bit_cast(h2_t, vc.x);
                const h2_t  vb = __builtin_bit_cast(h2_t, vc.y);
#pragma unroll
                for (int rr = 0; rr < 8; ++rr) {
                    h2_t s0 = u2[rr][0] + va;
                    h2_t s1 = u2[rr][1] + vb;
                    s0 = __builtin_elementwise_max(s0, zero);
                    s1 = __builtin_elementwise_max(s1, zero);
                    acc[rr] = __builtin_amdgcn_fdot2(s0, w2h[0], acc[rr], false);
                    acc[rr] = __builtin_amdgcn_fdot2(s1, w2h[1], acc[rr], false);
                }
                vc = vn;
            }
        }
        // kg-reduce in-register (lane bits 0-2)
#pragma unroll
        for (int m = 1; m <= 4; m <<= 1)
#pragma unroll
            for (int rr = 0; rr < 8; ++rr) acc[rr] += __shfl_xor(acc[rr], m);
        if (kg == 0) {
            *(float4*)&u_s.m.part[jg][rg][0] = make_float4(acc[0], acc[1], acc[2], acc[3]);
            *(float4*)&u_s.m.part[jg][rg][4] = make_float4(acc[4], acc[5], acc[6], acc[7]);
        }
        __syncthreads();

        if (t < NN) {
            float m = (float)NN * aux_s[352];
#pragma unroll
            for (int g = 0; g < 4; ++g) m += u_s.m.part[g][t >> 3][t & 7];
            u_s.m.msg[t] = m;
        }
        __syncthreads();

        // ---- stage p: chunk-major p4[c][row] ----
#pragma unroll
        for (int it = 0; it < 2; ++it) {
            const int   row = t & 127;
            const int   c   = (t >> 7) + it * 4;
            const float mi  = u_s.m.msg[row];
            const float cr  = (float)row * (1.0f / (float)NN);
            const int   k0  = c * 4;
            float4 p;
            p.x = mi * aux_s[128 + k0 + 0] + cr * aux_s[160 + k0 + 0] + aux_s[224 + k0 + 0];
            p.y = mi * aux_s[128 + k0 + 1] + cr * aux_s[160 + k0 + 1] + aux_s[224 + k0 + 1];
            p.z = mi * aux_s[128 + k0 + 2] + cr * aux_s[160 + k0 + 2] + aux_s[224 + k0 + 2];
            p.w = mi * aux_s[128 + k0 + 3] + cr * aux_s[160 + k0 + 3] + aux_s[224 + k0 + 3];
            u_s.m.p4[c][row] = p;
        }
        __syncthreads();

        // ---- stage 2: a = t>>5 (16 groups, a=15 dummy), sub = t&31, rows sub+32m ----
        {
            const int   a   = t >> 5;
            const int   sub = t & 31;
            const float fa  = (float)a;
            float qa[HH];
#pragma unroll
            for (int k = 0; k < HH; ++k) qa[k] = fa * aux_s[192 + k];
            float s0 = 0.f, s1 = 0.f, s2 = 0.f, s3 = 0.f;
#pragma unroll
            for (int m = 0; m < 4; ++m) {
                const int row = sub + 32 * m;
#pragma unroll
                for (int c = 0; c < 8; ++c) {
                    const float4 p4 = u_s.m.p4[c][row];
                    const float4 w4 = *(const float4*)&aux_s[256 + c * 4];
                    const int    k0 = c * 4;
                    s0 += fmaxf(p4.x + qa[k0 + 0], 0.f) * w4.x;
                    s1 += fmaxf(p4.y + qa[k0 + 1], 0.f) * w4.y;
                    s2 += fmaxf(p4.z + qa[k0 + 2], 0.f) * w4.z;
                    s3 += fmaxf(p4.w + qa[k0 + 3], 0.f) * w4.w;
                }
            }
            float s = (s0 + s1) + (s2 + s3);
#pragma unroll
            for (int off = 1; off < 32; off <<= 1) s += __shfl_xor(s, off);
            if (sub == 0 && a < AA)
                out[b * AA + a] = s + (float)NN * aux_s[353];
        }
    } else {
        // ===================== critic: MFMA, 16 batch elems per block =====================
        const int b0 = blk * 16;

        // obs -> f16 A-buffer 0
        for (int e = t; e < 16 * NN; e += 512)
            u_s.c.hA[0][e >> 7][e & 127] = (_Float16)obs[(b0 + (e >> 7)) * NN + (e & 127)];
        __syncthreads();

        const int w    = t >> 6;            // wave: N-tiles w*32, w*32+16
        const int arow = lane & 15;         // A row / B col / D col selector
        const int koff = (lane >> 4) * 8;   // contiguous k start within K=32 step
        const int n0   = w * 32;

        auto critLayer = [&](const _Float16 (&Ain)[16][264], _Float16 (&Aout)[16][264],
                             const float* __restrict__ W, const float* __restrict__ bias,
                             const int Kd) {
            f32x4 acc0 = {0.f, 0.f, 0.f, 0.f};
            f32x4 acc1 = {0.f, 0.f, 0.f, 0.f};
            for (int ks = 0; ks < Kd; ks += 32) {
                const f16x8  af = *(const f16x8*)&Ain[arow][ks + koff];
                const float* wp = W + (size_t)(ks + koff) * MIDD + n0 + arow;
                f16x8 bf0, bf1;
#pragma unroll
                for (int j = 0; j < 8; ++j) {
                    bf0[j] = (_Float16)wp[j * MIDD];
                    bf1[j] = (_Float16)wp[j * MIDD + 16];
                }
                acc0 = __builtin_amdgcn_mfma_f32_16x16x32_f16(af, bf0, acc0, 0, 0, 0);
                acc1 = __builtin_amdgcn_mfma_f32_16x16x32_f16(af, bf1, acc1, 0, 0, 0);
            }
            const float b0v = bias[n0 + arow];
            const float b1v = bias[n0 + 16 + arow];
#pragma unroll
            for (int reg = 0; reg < 4; ++reg) {
                const int i = (lane >> 4) * 4 + reg;
                Aout[i][n0 + arow]      = (_Float16)fmaxf(acc0[reg] + b0v, 0.f);
                Aout[i][n0 + 16 + arow] = (_Float16)fmaxf(acc1[reg] + b1v, 0.f);
            }
        };

        critLayer(u_s.c.hA[0], u_s.c.hA[1], cw1, cb1, 128);
        __syncthreads();
        critLayer(u_s.c.hA[1], u_s.c.hA[0], cw2, cb2, 256);
        __syncthreads();
        critLayer(u_s.c.hA[0], u_s.c.hA[1], cw3, cb3, 256);
        __syncthreads();

        // head: value_i = sum_n h3[i][n]*cw4[n] + cb4
        {
            const int i  = t >> 5;      // batch elem 0..15
            const int sl = t & 31;      // 8-wide n slice
            float s = 0.f;
#pragma unroll
            for (int j = 0; j < 8; ++j)
                s += (float)u_s.c.hA[1][i][sl * 8 + j] * cw4[sl * 8 + j];
#pragma unroll
            for (int off = 1; off < 32; off <<= 1) s += __shfl_xor(s, off);
            if (sl == 0) out[BB * AA + b0 + i] = s + cb4[0];
        }
    }
}

extern "C" void kernel_launch(void* const* d_in, const int* in_sizes, int n_in,
                              void* d_out, int out_size, void* d_ws, size_t ws_size,
                              hipStream_t stream) {
    const float* obs = (const float*)d_in[0];
    const float* mw1 = (const float*)d_in[1];
    const float* mb1 = (const float*)d_in[2];
    const float* mw2 = (const float*)d_in[3];
    const float* mb2 = (const float*)d_in[4];
    const float* aw1 = (const float*)d_in[5];
    const float* ab1 = (const float*)d_in[6];
    const float* aw2 = (const float*)d_in[7];
    const float* ab2 = (const float*)d_in[8];
    const float* cw1 = (const float*)d_in[9];
    const float* cb1 = (const float*)d_in[10];
    const float* cw2 = (const float*)d_in[11];
    const float* cb2 = (const float*)d_in[12];
    const float* cw3 = (const float*)d_in[13];
    const float* cb3 = (const float*)d_in[14];
    const float* cw4 = (const float*)d_in[15];
    const float* cb4 = (const float*)d_in[16];
    float* out = (float*)d_out;

    gacq_v9<<<dim3(BB + NCRIT), dim3(512), 0, stream>>>(
        obs, mw1, mb1, mw2, mb2, aw1, ab1, aw2, ab2,
        cw1, cb1, cw2, cb2, cw3, cb3, cw4, cb4, out);
}